// Round 4
// baseline (5947.324 us; speedup 1.0000x reference)
//
#include <hip/hip_runtime.h>
#include <hip/hip_fp16.h>

#define NN 100000
#define NE 1600000
#define HD 128
#define HD2 256

typedef unsigned int u32;
typedef unsigned short u16;
typedef _Float16 half8 __attribute__((ext_vector_type(8)));
typedef float floatx4 __attribute__((ext_vector_type(4)));

static inline int cdiv(int a, int b){ return (a + b - 1) / b; }

// ---- split-fp16 packing: x ~= h + l * 2^-12, l pre-scaled by 4096 ----
__device__ __forceinline__ u32 split_pack(float v){
  __half h;
  if(fabsf(v) < 6.103515625e-05f) h = __ushort_as_half((u16)0);
  else h = __float2half_rn(v);
  float hf = __half2float(h);
  __half l = __float2half_rn((v - hf) * 4096.0f);
  return (u32)__half_as_ushort(h) | ((u32)__half_as_ushort(l) << 16);
}

// merge 8 packed u32 into ushort8-of-h and ushort8-of-l (3 ops per output word)
__device__ __forceinline__ void unpack8(uint4 p0, uint4 p1, uint4& h, uint4& l){
  h.x = (p0.x & 0xffffu) | (p0.y << 16);
  h.y = (p0.z & 0xffffu) | (p0.w << 16);
  h.z = (p1.x & 0xffffu) | (p1.y << 16);
  h.w = (p1.z & 0xffffu) | (p1.w << 16);
  l.x = (p0.x >> 16) | (p0.y & 0xffff0000u);
  l.y = (p0.z >> 16) | (p0.w & 0xffff0000u);
  l.z = (p1.x >> 16) | (p1.y & 0xffff0000u);
  l.w = (p1.z >> 16) | (p1.w & 0xffff0000u);
}

// ---------------- utility kernels ----------------
__global__ void k_zero_int(int* __restrict__ p, int n){
  int i = blockIdx.x * 256 + threadIdx.x;
  if(i < n) p[i] = 0;
}

__global__ void k_zero_f2(float* __restrict__ a, float* __restrict__ b, int n){
  int i = blockIdx.x * 256 + threadIdx.x;
  if(i < n){ a[i] = 0.f; b[i] = 0.f; }
}

__global__ void k_hist(const int* __restrict__ rows, int* __restrict__ cnt){
  int e = blockIdx.x * 256 + threadIdx.x;
  if(e < NE) atomicAdd(&cnt[rows[e]], 1);
}

__global__ void k_scan1(const int* __restrict__ cnt, int* __restrict__ part,
                        int* __restrict__ sums, int n){
  __shared__ int sh[256];
  int tid = threadIdx.x;
  int base = blockIdx.x * 1024 + tid * 4;
  int v0 = (base + 0 < n) ? cnt[base + 0] : 0;
  int v1 = (base + 1 < n) ? cnt[base + 1] : 0;
  int v2 = (base + 2 < n) ? cnt[base + 2] : 0;
  int v3 = (base + 3 < n) ? cnt[base + 3] : 0;
  int s = v0 + v1 + v2 + v3;
  sh[tid] = s;
  __syncthreads();
  for(int d = 1; d < 256; d <<= 1){
    int t = (tid >= d) ? sh[tid - d] : 0;
    __syncthreads();
    sh[tid] += t;
    __syncthreads();
  }
  int excl = sh[tid] - s;
  if(tid == 255) sums[blockIdx.x] = sh[255];
  if(base + 0 < n) part[base + 0] = excl;
  if(base + 1 < n) part[base + 1] = excl + v0;
  if(base + 2 < n) part[base + 2] = excl + v0 + v1;
  if(base + 3 < n) part[base + 3] = excl + v0 + v1 + v2;
}

__global__ void k_scan2(int* __restrict__ sums, int nb){
  __shared__ int sh[128];
  int tid = threadIdx.x;
  int v = (tid < nb) ? sums[tid] : 0;
  sh[tid] = v;
  __syncthreads();
  for(int d = 1; d < 128; d <<= 1){
    int t = (tid >= d) ? sh[tid - d] : 0;
    __syncthreads();
    sh[tid] += t;
    __syncthreads();
  }
  if(tid < nb) sums[tid] = sh[tid] - v;
}

__global__ void k_scan3(int* __restrict__ rowptr, int* __restrict__ cursor,
                        const int* __restrict__ sums, int n){
  int tid = threadIdx.x;
  int off = sums[blockIdx.x];
  int base = blockIdx.x * 1024 + tid * 4;
  #pragma unroll
  for(int j = 0; j < 4; j++){
    int idx = base + j;
    if(idx < n){ int r = rowptr[idx] + off; rowptr[idx] = r; cursor[idx] = r; }
  }
  if(blockIdx.x == 0 && tid == 0) rowptr[n] = NE;
}

__global__ void k_scatter(const int* __restrict__ rows, const int* __restrict__ cols,
                          const float* __restrict__ vals, int* __restrict__ cursor,
                          int* __restrict__ ocol, float* __restrict__ oval){
  int e = blockIdx.x * 256 + threadIdx.x;
  if(e < NE){
    int r = rows[e];
    int pp = atomicAdd(&cursor[r], 1);
    ocol[pp] = cols[e];
    oval[pp] = vals[e];
  }
}

// weight pre-split: W is [K][N] row-major fp32; out: h/l ushort arrays, [N][K] (transposed)
__global__ void k_splitw(const float* __restrict__ W, u16* __restrict__ oh,
                         u16* __restrict__ ol, int K, int N, int total){
  int idx = blockIdx.x * 256 + threadIdx.x;
  if(idx < total){
    int n = idx / K, k = idx - n * K;
    u32 p = split_pack(W[(size_t)k * N + n]);
    oh[idx] = (u16)(p & 0xffffu);
    ol[idx] = (u16)(p >> 16);
  }
}

// ---------------- SpMM: one wave per node; relu (+ optional l2norm); packed-split output ----
template<bool NORM>
__global__ void k_spmm(const int* __restrict__ rowptr, const int* __restrict__ col,
                       const float* __restrict__ val, const float* __restrict__ X,
                       u32* __restrict__ outpk){
  int node = (blockIdx.x << 2) + (threadIdx.x >> 6);
  int lane = threadIdx.x & 63;
  if(node >= NN) return;
  int s = rowptr[node], e = rowptr[node + 1];
  float ax = 0.f, ay = 0.f, bx = 0.f, by = 0.f;
  float cx = 0.f, cy = 0.f, dx = 0.f, dy = 0.f;
  int i = s;
  for(; i + 7 < e; i += 8){
    int   c0 = col[i],     c1 = col[i + 1], c2 = col[i + 2], c3 = col[i + 3];
    int   c4 = col[i + 4], c5 = col[i + 5], c6 = col[i + 6], c7 = col[i + 7];
    float v0 = val[i],     v1 = val[i + 1], v2 = val[i + 2], v3 = val[i + 3];
    float v4 = val[i + 4], v5 = val[i + 5], v6 = val[i + 6], v7 = val[i + 7];
    float2 x0 = *(const float2*)(X + (size_t)c0 * HD + lane * 2);
    float2 x1 = *(const float2*)(X + (size_t)c1 * HD + lane * 2);
    float2 x2 = *(const float2*)(X + (size_t)c2 * HD + lane * 2);
    float2 x3 = *(const float2*)(X + (size_t)c3 * HD + lane * 2);
    float2 x4 = *(const float2*)(X + (size_t)c4 * HD + lane * 2);
    float2 x5 = *(const float2*)(X + (size_t)c5 * HD + lane * 2);
    float2 x6 = *(const float2*)(X + (size_t)c6 * HD + lane * 2);
    float2 x7 = *(const float2*)(X + (size_t)c7 * HD + lane * 2);
    ax += v0 * x0.x + v1 * x1.x;  ay += v0 * x0.y + v1 * x1.y;
    bx += v2 * x2.x + v3 * x3.x;  by += v2 * x2.y + v3 * x3.y;
    cx += v4 * x4.x + v5 * x5.x;  cy += v4 * x4.y + v5 * x5.y;
    dx += v6 * x6.x + v7 * x7.x;  dy += v6 * x6.y + v7 * x7.y;
  }
  for(; i + 1 < e; i += 2){
    int   c0 = col[i],   c1 = col[i + 1];
    float v0 = val[i],   v1 = val[i + 1];
    float2 x0 = *(const float2*)(X + (size_t)c0 * HD + lane * 2);
    float2 x1 = *(const float2*)(X + (size_t)c1 * HD + lane * 2);
    ax += v0 * x0.x + v1 * x1.x;  ay += v0 * x0.y + v1 * x1.y;
  }
  if(i < e){
    int c = col[i]; float v = val[i];
    float2 xv = *(const float2*)(X + (size_t)c * HD + lane * 2);
    ax += v * xv.x; ay += v * xv.y;
  }
  ax += bx + cx + dx;
  ay += by + cy + dy;
  ax = fmaxf(ax, 0.f);
  ay = fmaxf(ay, 0.f);
  if(NORM){
    float ss = ax * ax + ay * ay;
    #pragma unroll
    for(int o = 32; o >= 1; o >>= 1) ss += __shfl_xor(ss, o, 64);
    float scale = 1.f / fmaxf(sqrtf(ss), 1e-12f);
    ax *= scale; ay *= scale;
  }
  *(uint2*)(outpk + (size_t)node * HD + lane * 2) = make_uint2(split_pack(ax), split_pack(ay));
}

// ---------------- split-fp16 MFMA GEMM ----------------
// A: packed u32 [M][K]; B: pre-split h/l ushort [N][K] (transposed).
// MODE 0: Yout = A@B (fp32). MODE 1: Hout = pack(relu(A@B+bias)).
// MODE 2: score[m] += sum_n relu(A@B+bias)[m][n]*m3[n].
template<int MODE, int KK>
__launch_bounds__(256, 2)
__global__ void k_mfma_gemm(const u32* __restrict__ Apk, const u16* __restrict__ Bth,
                            const u16* __restrict__ Btl, const float* __restrict__ bias,
                            float* __restrict__ Yout, u32* __restrict__ Hout,
                            const float* __restrict__ m3, float* __restrict__ score,
                            int M, int N){
  __shared__ u16 As_h[128 * 40], As_l[128 * 40];
  __shared__ u16 Bs_h[128 * 40], Bs_l[128 * 40];
  const int tid = threadIdx.x;
  const int lane = tid & 63, wid = tid >> 6;
  const int lm = lane & 15, lg = lane >> 4;
  const int mq = (wid & 1) * 64, nq = (wid >> 1) * 64;
  const int m0 = blockIdx.x * 128, n0 = blockIdx.y * 128;

  floatx4 accA[4][4], accB[4][4];
  #pragma unroll
  for(int i = 0; i < 4; i++)
    #pragma unroll
    for(int j = 0; j < 4; j++){
      accA[i][j] = (floatx4){0.f, 0.f, 0.f, 0.f};
      accB[i][j] = (floatx4){0.f, 0.f, 0.f, 0.f};
    }

  const int r0 = tid >> 2;            // 0..63 (j-iter adds 64)
  const int kc = (tid & 3) * 8;       // 0,8,16,24
  #pragma unroll 1
  for(int k0 = 0; k0 < KK; k0 += 32){
    uint4 a0[2], a1[2], bh[2], bl[2];
    #pragma unroll
    for(int j = 0; j < 2; j++){
      int row = r0 + j * 64;
      int ar = m0 + row; if(ar >= M) ar = M - 1;
      const u32* pa = Apk + (size_t)ar * KK + k0 + kc;
      a0[j] = *(const uint4*)pa;
      a1[j] = *(const uint4*)(pa + 4);
      const u16* ph = Bth + (size_t)(n0 + row) * KK + k0 + kc;
      const u16* pl = Btl + (size_t)(n0 + row) * KK + k0 + kc;
      bh[j] = *(const uint4*)ph;
      bl[j] = *(const uint4*)pl;
    }
    if(k0) __syncthreads();
    #pragma unroll
    for(int j = 0; j < 2; j++){
      int row = r0 + j * 64;
      int base = row * 40 + kc;
      uint4 h, l;
      unpack8(a0[j], a1[j], h, l);
      *(uint4*)&As_h[base] = h;
      *(uint4*)&As_l[base] = l;
      *(uint4*)&Bs_h[base] = bh[j];
      *(uint4*)&Bs_l[base] = bl[j];
    }
    __syncthreads();

    half8 fa_h[4], fa_l[4], fb_h[4], fb_l[4];
    #pragma unroll
    for(int s = 0; s < 4; s++){
      int ra = (mq + s * 16 + lm) * 40 + lg * 8;
      fa_h[s] = *(const half8*)&As_h[ra];
      fa_l[s] = *(const half8*)&As_l[ra];
      int rb = (nq + s * 16 + lm) * 40 + lg * 8;
      fb_h[s] = *(const half8*)&Bs_h[rb];
      fb_l[s] = *(const half8*)&Bs_l[rb];
    }
    #pragma unroll
    for(int i = 0; i < 4; i++)
      #pragma unroll
      for(int j = 0; j < 4; j++){
        accA[i][j] = __builtin_amdgcn_mfma_f32_16x16x32_f16(fa_h[i], fb_h[j], accA[i][j], 0, 0, 0);
        accB[i][j] = __builtin_amdgcn_mfma_f32_16x16x32_f16(fa_h[i], fb_l[j], accB[i][j], 0, 0, 0);
        accB[i][j] = __builtin_amdgcn_mfma_f32_16x16x32_f16(fa_l[i], fb_h[j], accB[i][j], 0, 0, 0);
      }
  }

  const float inv4096 = 1.f / 4096.f;
  if(MODE == 0){
    #pragma unroll
    for(int i = 0; i < 4; i++)
      #pragma unroll
      for(int r = 0; r < 4; r++){
        int m = m0 + mq + i * 16 + lg * 4 + r;
        if(m < M){
          #pragma unroll
          for(int j = 0; j < 4; j++){
            int c = n0 + nq + j * 16 + lm;
            Yout[(size_t)m * N + c] = accA[i][j][r] + accB[i][j][r] * inv4096;
          }
        }
      }
  } else if(MODE == 1){
    #pragma unroll
    for(int i = 0; i < 4; i++)
      #pragma unroll
      for(int r = 0; r < 4; r++){
        int m = m0 + mq + i * 16 + lg * 4 + r;
        if(m < M){
          #pragma unroll
          for(int j = 0; j < 4; j++){
            int c = n0 + nq + j * 16 + lm;
            float v = fmaxf(accA[i][j][r] + accB[i][j][r] * inv4096 + bias[c], 0.f);
            Hout[(size_t)m * N + c] = split_pack(v);
          }
        }
      }
  } else {
    #pragma unroll
    for(int i = 0; i < 4; i++)
      #pragma unroll
      for(int r = 0; r < 4; r++){
        float s = 0.f;
        #pragma unroll
        for(int j = 0; j < 4; j++){
          int c = n0 + nq + j * 16 + lm;
          float v = fmaxf(accA[i][j][r] + accB[i][j][r] * inv4096 + bias[c], 0.f);
          s = fmaf(v, m3[c], s);
        }
        s += __shfl_xor(s, 1, 64);
        s += __shfl_xor(s, 2, 64);
        s += __shfl_xor(s, 4, 64);
        s += __shfl_xor(s, 8, 64);
        int m = m0 + mq + i * 16 + lg * 4 + r;
        if(lm == 0 && m < M) atomicAdd(&score[m], s);
      }
  }
}

__global__ void k_final(const float* __restrict__ s1, const float* __restrict__ s2,
                        const float* __restrict__ b3, float* __restrict__ out){
  int i = blockIdx.x * 256 + threadIdx.x;
  if(i < NN){
    float b = 9.f * b3[0];
    out[i] = (s1[i] + b) * (s2[i] + b);
  }
}

// ---------------- launcher ----------------
extern "C" void kernel_launch(void* const* d_in, const int* in_sizes, int n_in,
                              void* d_out, int out_size, void* d_ws, size_t ws_size,
                              hipStream_t stream){
  const int*   a1r = (const int*)d_in[0];
  const int*   a1c = (const int*)d_in[1];
  const float* a1v = (const float*)d_in[2];
  const int*   a2r = (const int*)d_in[3];
  const int*   a2c = (const int*)d_in[4];
  const float* a2v = (const float*)d_in[5];
  const float* w1  = (const float*)d_in[6];
  const float* w[8];
  for(int i = 0; i < 8; i++) w[i] = (const float*)d_in[7 + i];
  const float* m1 = (const float*)d_in[15];
  const float* b1 = (const float*)d_in[16];
  const float* m2 = (const float*)d_in[17];
  const float* b2 = (const float*)d_in[18];
  const float* m3 = (const float*)d_in[19];
  const float* b3 = (const float*)d_in[20];
  float* out = (float*)d_out;

  char* base = (char*)d_ws;
  size_t off = 0;
  auto alloc = [&](size_t bytes) -> char* {
    char* r = base + off;
    off += (bytes + 255) & ~(size_t)255;
    return r;
  };
  int*   c1ptr = (int*)  alloc((size_t)(NN + 1) * 4);
  int*   c1col = (int*)  alloc((size_t)NE * 4);
  float* c1val = (float*)alloc((size_t)NE * 4);
  int*   c2ptr = (int*)  alloc((size_t)(NN + 1) * 4);
  int*   c2col = (int*)  alloc((size_t)NE * 4);
  float* c2val = (float*)alloc((size_t)NE * 4);
  int*   cursor= (int*)  alloc((size_t)NN * 4);
  int*   sums  = (int*)  alloc(512);
  u32*   xpk   = (u32*)  alloc((size_t)NN * HD * 4);     // packed split x
  u32*   h1pk  = (u32*)  alloc((size_t)NN * HD2 * 4);    // packed split h1; y aliases front half
  float* sc1   = (float*)alloc((size_t)NN * 4);
  float* sc2   = (float*)alloc((size_t)NN * 4);
  u16 *wth[8], *wtl[8];
  for(int i = 0; i < 8; i++){
    wth[i] = (u16*)alloc((size_t)HD * HD * 2);
    wtl[i] = (u16*)alloc((size_t)HD * HD * 2);
  }
  u16* m1th = (u16*)alloc((size_t)HD2 * HD * 2);
  u16* m1tl = (u16*)alloc((size_t)HD2 * HD * 2);
  u16* m2th = (u16*)alloc((size_t)HD2 * HD2 * 2);
  u16* m2tl = (u16*)alloc((size_t)HD2 * HD2 * 2);
  float* y = (float*)h1pk;   // [NN][128] fp32; dead before h1pk is written (sequential kernels)

  const int SCAN_BLOCKS = cdiv(NN, 1024);
  auto build_csr = [&](const int* rows, const int* cols, const float* vals,
                       int* rptr, int* rcol, float* rval){
    hipLaunchKernelGGL(k_zero_int, dim3(cdiv(NN, 256)), dim3(256), 0, stream, cursor, NN);
    hipLaunchKernelGGL(k_hist,     dim3(cdiv(NE, 256)), dim3(256), 0, stream, rows, cursor);
    hipLaunchKernelGGL(k_scan1,    dim3(SCAN_BLOCKS),   dim3(256), 0, stream, cursor, rptr, sums, NN);
    hipLaunchKernelGGL(k_scan2,    dim3(1),             dim3(128), 0, stream, sums, SCAN_BLOCKS);
    hipLaunchKernelGGL(k_scan3,    dim3(SCAN_BLOCKS),   dim3(256), 0, stream, rptr, cursor, sums, NN);
    hipLaunchKernelGGL(k_scatter,  dim3(cdiv(NE, 256)), dim3(256), 0, stream, rows, cols, vals, cursor, rcol, rval);
  };

  auto splitw = [&](const float* W, u16* oh, u16* ol, int K, int N){
    int total = K * N;
    hipLaunchKernelGGL(k_splitw, dim3(cdiv(total, 256)), dim3(256), 0, stream, W, oh, ol, K, N, total);
  };
  for(int i = 0; i < 8; i++) splitw(w[i], wth[i], wtl[i], HD, HD);
  splitw(m1, m1th, m1tl, HD, HD2);
  splitw(m2, m2th, m2tl, HD2, HD2);

  const int GX = cdiv(NN, 128);   // 782
  auto mlp = [&](float* score){
    hipLaunchKernelGGL((k_mfma_gemm<1, HD>), dim3(GX, 2), dim3(256), 0, stream,
                       xpk, m1th, m1tl, b1, (float*)nullptr, h1pk,
                       (const float*)nullptr, (float*)nullptr, NN, HD2);
    hipLaunchKernelGGL((k_mfma_gemm<2, HD2>), dim3(GX, 2), dim3(256), 0, stream,
                       h1pk, m2th, m2tl, b2, (float*)nullptr, (u32*)nullptr,
                       m3, score, NN, HD2);
  };

  auto branch = [&](const int* rptr, const int* rcol, const float* rval, float* score){
    hipLaunchKernelGGL((k_spmm<true>), dim3(cdiv(NN, 4)), dim3(256), 0, stream,
                       rptr, rcol, rval, w1, xpk);
    mlp(score);
    for(int i = 0; i < 8; i++){
      hipLaunchKernelGGL((k_mfma_gemm<0, HD>), dim3(GX, 1), dim3(256), 0, stream,
                         xpk, wth[i], wtl[i], (const float*)nullptr, y, (u32*)nullptr,
                         (const float*)nullptr, (float*)nullptr, NN, HD);
      if(i < 7)
        hipLaunchKernelGGL((k_spmm<true>),  dim3(cdiv(NN, 4)), dim3(256), 0, stream,
                           rptr, rcol, rval, y, xpk);
      else
        hipLaunchKernelGGL((k_spmm<false>), dim3(cdiv(NN, 4)), dim3(256), 0, stream,
                           rptr, rcol, rval, y, xpk);
      mlp(score);
    }
  };

  build_csr(a1r, a1c, a1v, c1ptr, c1col, c1val);
  build_csr(a2r, a2c, a2v, c2ptr, c2col, c2val);
  hipLaunchKernelGGL(k_zero_f2, dim3(cdiv(NN, 256)), dim3(256), 0, stream, sc1, sc2, NN);
  branch(c1ptr, c1col, c1val, sc1);
  branch(c2ptr, c2col, c2val, sc2);
  hipLaunchKernelGGL(k_final, dim3(cdiv(NN, 256)), dim3(256), 0, stream, sc1, sc2, b3, out);
}

// Round 5
// 4860.477 us; speedup vs baseline: 1.2236x; 1.2236x over previous
//
#include <hip/hip_runtime.h>
#include <hip/hip_fp16.h>

#define NN 100000
#define NE 1600000
#define HD 128
#define HD2 256

typedef unsigned int u32;
typedef unsigned short u16;
typedef _Float16 half8 __attribute__((ext_vector_type(8)));
typedef float floatx4 __attribute__((ext_vector_type(4)));

static inline int cdiv(int a, int b){ return (a + b - 1) / b; }

// ---- split-fp16 packing: x ~= h + l * 2^-12, l pre-scaled by 4096 ----
__device__ __forceinline__ u32 split_pack(float v){
  __half h;
  if(fabsf(v) < 6.103515625e-05f) h = __ushort_as_half((u16)0);
  else h = __float2half_rn(v);
  float hf = __half2float(h);
  __half l = __float2half_rn((v - hf) * 4096.0f);
  return (u32)__half_as_ushort(h) | ((u32)__half_as_ushort(l) << 16);
}

// ---------------- utility kernels ----------------
__global__ void k_zero_int(int* __restrict__ p, int n){
  int i = blockIdx.x * 256 + threadIdx.x;
  if(i < n) p[i] = 0;
}

__global__ void k_zero_f2(float* __restrict__ a, float* __restrict__ b, int n){
  int i = blockIdx.x * 256 + threadIdx.x;
  if(i < n){ a[i] = 0.f; b[i] = 0.f; }
}

__global__ void k_hist(const int* __restrict__ rows, int* __restrict__ cnt){
  int e = blockIdx.x * 256 + threadIdx.x;
  if(e < NE) atomicAdd(&cnt[rows[e]], 1);
}

__global__ void k_scan1(const int* __restrict__ cnt, int* __restrict__ part,
                        int* __restrict__ sums, int n){
  __shared__ int sh[256];
  int tid = threadIdx.x;
  int base = blockIdx.x * 1024 + tid * 4;
  int v0 = (base + 0 < n) ? cnt[base + 0] : 0;
  int v1 = (base + 1 < n) ? cnt[base + 1] : 0;
  int v2 = (base + 2 < n) ? cnt[base + 2] : 0;
  int v3 = (base + 3 < n) ? cnt[base + 3] : 0;
  int s = v0 + v1 + v2 + v3;
  sh[tid] = s;
  __syncthreads();
  for(int d = 1; d < 256; d <<= 1){
    int t = (tid >= d) ? sh[tid - d] : 0;
    __syncthreads();
    sh[tid] += t;
    __syncthreads();
  }
  int excl = sh[tid] - s;
  if(tid == 255) sums[blockIdx.x] = sh[255];
  if(base + 0 < n) part[base + 0] = excl;
  if(base + 1 < n) part[base + 1] = excl + v0;
  if(base + 2 < n) part[base + 2] = excl + v0 + v1;
  if(base + 3 < n) part[base + 3] = excl + v0 + v1 + v2;
}

__global__ void k_scan2(int* __restrict__ sums, int nb){
  __shared__ int sh[128];
  int tid = threadIdx.x;
  int v = (tid < nb) ? sums[tid] : 0;
  sh[tid] = v;
  __syncthreads();
  for(int d = 1; d < 128; d <<= 1){
    int t = (tid >= d) ? sh[tid - d] : 0;
    __syncthreads();
    sh[tid] += t;
    __syncthreads();
  }
  if(tid < nb) sums[tid] = sh[tid] - v;
}

__global__ void k_scan3(int* __restrict__ rowptr, int* __restrict__ cursor,
                        const int* __restrict__ sums, int n){
  int tid = threadIdx.x;
  int off = sums[blockIdx.x];
  int base = blockIdx.x * 1024 + tid * 4;
  #pragma unroll
  for(int j = 0; j < 4; j++){
    int idx = base + j;
    if(idx < n){ int r = rowptr[idx] + off; rowptr[idx] = r; cursor[idx] = r; }
  }
  if(blockIdx.x == 0 && tid == 0) rowptr[n] = NE;
}

__global__ void k_scatter(const int* __restrict__ rows, const int* __restrict__ cols,
                          const float* __restrict__ vals, int* __restrict__ cursor,
                          int* __restrict__ ocol, float* __restrict__ oval){
  int e = blockIdx.x * 256 + threadIdx.x;
  if(e < NE){
    int r = rows[e];
    int pp = atomicAdd(&cursor[r], 1);
    ocol[pp] = cols[e];
    oval[pp] = vals[e];
  }
}

// weight pre-split: W is [K][N] row-major fp32; out is packed [N][K] (transposed)
__global__ void k_splitw(const float* __restrict__ W, u32* __restrict__ out,
                         int K, int N, int total){
  int idx = blockIdx.x * 256 + threadIdx.x;
  if(idx < total){
    int n = idx / K, k = idx - n * K;
    out[idx] = split_pack(W[(size_t)k * N + n]);
  }
}

// ---------------- SpMM: one wave per node; relu (+ optional l2norm); packed-split output ----
template<bool NORM>
__global__ void k_spmm(const int* __restrict__ rowptr, const int* __restrict__ col,
                       const float* __restrict__ val, const float* __restrict__ X,
                       u32* __restrict__ outpk){
  int node = (blockIdx.x << 2) + (threadIdx.x >> 6);
  int lane = threadIdx.x & 63;
  if(node >= NN) return;
  int s = rowptr[node], e = rowptr[node + 1];
  float ax = 0.f, ay = 0.f, bx = 0.f, by = 0.f;
  float cx = 0.f, cy = 0.f, dx = 0.f, dy = 0.f;
  int i = s;
  for(; i + 7 < e; i += 8){
    int   c0 = col[i],     c1 = col[i + 1], c2 = col[i + 2], c3 = col[i + 3];
    int   c4 = col[i + 4], c5 = col[i + 5], c6 = col[i + 6], c7 = col[i + 7];
    float v0 = val[i],     v1 = val[i + 1], v2 = val[i + 2], v3 = val[i + 3];
    float v4 = val[i + 4], v5 = val[i + 5], v6 = val[i + 6], v7 = val[i + 7];
    float2 x0 = *(const float2*)(X + (size_t)c0 * HD + lane * 2);
    float2 x1 = *(const float2*)(X + (size_t)c1 * HD + lane * 2);
    float2 x2 = *(const float2*)(X + (size_t)c2 * HD + lane * 2);
    float2 x3 = *(const float2*)(X + (size_t)c3 * HD + lane * 2);
    float2 x4 = *(const float2*)(X + (size_t)c4 * HD + lane * 2);
    float2 x5 = *(const float2*)(X + (size_t)c5 * HD + lane * 2);
    float2 x6 = *(const float2*)(X + (size_t)c6 * HD + lane * 2);
    float2 x7 = *(const float2*)(X + (size_t)c7 * HD + lane * 2);
    ax += v0 * x0.x + v1 * x1.x;  ay += v0 * x0.y + v1 * x1.y;
    bx += v2 * x2.x + v3 * x3.x;  by += v2 * x2.y + v3 * x3.y;
    cx += v4 * x4.x + v5 * x5.x;  cy += v4 * x4.y + v5 * x5.y;
    dx += v6 * x6.x + v7 * x7.x;  dy += v6 * x6.y + v7 * x7.y;
  }
  for(; i + 1 < e; i += 2){
    int   c0 = col[i],   c1 = col[i + 1];
    float v0 = val[i],   v1 = val[i + 1];
    float2 x0 = *(const float2*)(X + (size_t)c0 * HD + lane * 2);
    float2 x1 = *(const float2*)(X + (size_t)c1 * HD + lane * 2);
    ax += v0 * x0.x + v1 * x1.x;  ay += v0 * x0.y + v1 * x1.y;
  }
  if(i < e){
    int c = col[i]; float v = val[i];
    float2 xv = *(const float2*)(X + (size_t)c * HD + lane * 2);
    ax += v * xv.x; ay += v * xv.y;
  }
  ax += bx + cx + dx;
  ay += by + cy + dy;
  ax = fmaxf(ax, 0.f);
  ay = fmaxf(ay, 0.f);
  if(NORM){
    float ss = ax * ax + ay * ay;
    #pragma unroll
    for(int o = 32; o >= 1; o >>= 1) ss += __shfl_xor(ss, o, 64);
    float scale = 1.f / fmaxf(sqrtf(ss), 1e-12f);
    ax *= scale; ay *= scale;
  }
  *(uint2*)(outpk + (size_t)node * HD + lane * 2) = make_uint2(split_pack(ax), split_pack(ay));
}

// ---------------- split-fp16 MFMA GEMM (round-2 verbatim) ----------------
// A: packed [M][K]; Bt: packed [N][K] (pre-transposed).
// MODE 0: Yout[m][n] = A@B                       (fp32 out, no activation)
// MODE 1: Hout[m][n] = pack(relu(A@B + bias))    (packed split out)
// MODE 2: score[m]  += sum_n relu(A@B+bias)[m][n] * m3[n]   (atomic)
template<int MODE>
__launch_bounds__(256, 2)
__global__ void k_mfma_gemm(const u32* __restrict__ Apk, const u32* __restrict__ Btpk,
                            const float* __restrict__ bias, float* __restrict__ Yout,
                            u32* __restrict__ Hout, const float* __restrict__ m3,
                            float* __restrict__ score, int M, int K, int N){
  __shared__ unsigned short As_h[128 * 40], As_l[128 * 40];
  __shared__ unsigned short Bs_h[128 * 40], Bs_l[128 * 40];
  const int tid = threadIdx.x;
  const int lane = tid & 63, wid = tid >> 6;
  const int lm = lane & 15, lg = lane >> 4;
  const int mq = (wid & 1) * 64, nq = (wid >> 1) * 64;
  const int m0 = blockIdx.x * 128, n0 = blockIdx.y * 128;

  floatx4 accA[4][4], accB[4][4];
  #pragma unroll
  for(int i = 0; i < 4; i++)
    #pragma unroll
    for(int j = 0; j < 4; j++){
      accA[i][j] = (floatx4){0.f, 0.f, 0.f, 0.f};
      accB[i][j] = (floatx4){0.f, 0.f, 0.f, 0.f};
    }

  for(int k0 = 0; k0 < K; k0 += 32){
    uint4 av[4], bv[4];
    #pragma unroll
    for(int j = 0; j < 4; j++){
      int li = tid + j * 256;
      int row = li >> 3, kc = (li & 7) * 4;
      int ar = m0 + row; if(ar >= M) ar = M - 1;
      av[j] = *(const uint4*)(Apk + (size_t)ar * K + k0 + kc);
      bv[j] = *(const uint4*)(Btpk + (size_t)(n0 + row) * K + k0 + kc);
    }
    __syncthreads();
    #pragma unroll
    for(int j = 0; j < 4; j++){
      int li = tid + j * 256;
      int row = li >> 3, kc = (li & 7) * 4;
      int base = row * 40 + kc;
      ushort4 h, l;
      h.x = (u16)(av[j].x & 0xffff); l.x = (u16)(av[j].x >> 16);
      h.y = (u16)(av[j].y & 0xffff); l.y = (u16)(av[j].y >> 16);
      h.z = (u16)(av[j].z & 0xffff); l.z = (u16)(av[j].z >> 16);
      h.w = (u16)(av[j].w & 0xffff); l.w = (u16)(av[j].w >> 16);
      *(ushort4*)&As_h[base] = h;
      *(ushort4*)&As_l[base] = l;
      h.x = (u16)(bv[j].x & 0xffff); l.x = (u16)(bv[j].x >> 16);
      h.y = (u16)(bv[j].y & 0xffff); l.y = (u16)(bv[j].y >> 16);
      h.z = (u16)(bv[j].z & 0xffff); l.z = (u16)(bv[j].z >> 16);
      h.w = (u16)(bv[j].w & 0xffff); l.w = (u16)(bv[j].w >> 16);
      *(ushort4*)&Bs_h[base] = h;
      *(ushort4*)&Bs_l[base] = l;
    }
    __syncthreads();

    half8 fa_h[4], fa_l[4], fb_h[4], fb_l[4];
    #pragma unroll
    for(int s = 0; s < 4; s++){
      int ra = (mq + s * 16 + lm) * 40 + lg * 8;
      fa_h[s] = *(const half8*)&As_h[ra];
      fa_l[s] = *(const half8*)&As_l[ra];
      int rb = (nq + s * 16 + lm) * 40 + lg * 8;
      fb_h[s] = *(const half8*)&Bs_h[rb];
      fb_l[s] = *(const half8*)&Bs_l[rb];
    }
    #pragma unroll
    for(int i = 0; i < 4; i++)
      #pragma unroll
      for(int j = 0; j < 4; j++){
        accA[i][j] = __builtin_amdgcn_mfma_f32_16x16x32_f16(fa_h[i], fb_h[j], accA[i][j], 0, 0, 0);
        accB[i][j] = __builtin_amdgcn_mfma_f32_16x16x32_f16(fa_h[i], fb_l[j], accB[i][j], 0, 0, 0);
        accB[i][j] = __builtin_amdgcn_mfma_f32_16x16x32_f16(fa_l[i], fb_h[j], accB[i][j], 0, 0, 0);
      }
  }

  const float inv4096 = 1.f / 4096.f;
  if(MODE == 0){
    #pragma unroll
    for(int i = 0; i < 4; i++)
      #pragma unroll
      for(int r = 0; r < 4; r++){
        int m = m0 + mq + i * 16 + lg * 4 + r;
        if(m < M){
          #pragma unroll
          for(int j = 0; j < 4; j++){
            int c = n0 + nq + j * 16 + lm;
            Yout[(size_t)m * N + c] = accA[i][j][r] + accB[i][j][r] * inv4096;
          }
        }
      }
  } else if(MODE == 1){
    #pragma unroll
    for(int i = 0; i < 4; i++)
      #pragma unroll
      for(int r = 0; r < 4; r++){
        int m = m0 + mq + i * 16 + lg * 4 + r;
        if(m < M){
          #pragma unroll
          for(int j = 0; j < 4; j++){
            int c = n0 + nq + j * 16 + lm;
            float v = fmaxf(accA[i][j][r] + accB[i][j][r] * inv4096 + bias[c], 0.f);
            Hout[(size_t)m * N + c] = split_pack(v);
          }
        }
      }
  } else {
    #pragma unroll
    for(int i = 0; i < 4; i++)
      #pragma unroll
      for(int r = 0; r < 4; r++){
        float s = 0.f;
        #pragma unroll
        for(int j = 0; j < 4; j++){
          int c = n0 + nq + j * 16 + lm;
          float v = fmaxf(accA[i][j][r] + accB[i][j][r] * inv4096 + bias[c], 0.f);
          s = fmaf(v, m3[c], s);
        }
        s += __shfl_xor(s, 1, 64);
        s += __shfl_xor(s, 2, 64);
        s += __shfl_xor(s, 4, 64);
        s += __shfl_xor(s, 8, 64);
        int m = m0 + mq + i * 16 + lg * 4 + r;
        if(lm == 0 && m < M) atomicAdd(&score[m], s);
      }
  }
}

__global__ void k_final(const float* __restrict__ s1, const float* __restrict__ s2,
                        const float* __restrict__ b3, float* __restrict__ out){
  int i = blockIdx.x * 256 + threadIdx.x;
  if(i < NN){
    float b = 9.f * b3[0];
    out[i] = (s1[i] + b) * (s2[i] + b);
  }
}

// ---------------- launcher ----------------
extern "C" void kernel_launch(void* const* d_in, const int* in_sizes, int n_in,
                              void* d_out, int out_size, void* d_ws, size_t ws_size,
                              hipStream_t stream){
  const int*   a1r = (const int*)d_in[0];
  const int*   a1c = (const int*)d_in[1];
  const float* a1v = (const float*)d_in[2];
  const int*   a2r = (const int*)d_in[3];
  const int*   a2c = (const int*)d_in[4];
  const float* a2v = (const float*)d_in[5];
  const float* w1  = (const float*)d_in[6];
  const float* w[8];
  for(int i = 0; i < 8; i++) w[i] = (const float*)d_in[7 + i];
  const float* m1 = (const float*)d_in[15];
  const float* b1 = (const float*)d_in[16];
  const float* m2 = (const float*)d_in[17];
  const float* b2 = (const float*)d_in[18];
  const float* m3 = (const float*)d_in[19];
  const float* b3 = (const float*)d_in[20];
  float* out = (float*)d_out;

  char* base = (char*)d_ws;
  size_t off = 0;
  auto alloc = [&](size_t bytes) -> char* {
    char* r = base + off;
    off += (bytes + 255) & ~(size_t)255;
    return r;
  };
  int*   c1ptr = (int*)  alloc((size_t)(NN + 1) * 4);
  int*   c1col = (int*)  alloc((size_t)NE * 4);
  float* c1val = (float*)alloc((size_t)NE * 4);
  int*   c2ptr = (int*)  alloc((size_t)(NN + 1) * 4);
  int*   c2col = (int*)  alloc((size_t)NE * 4);
  float* c2val = (float*)alloc((size_t)NE * 4);
  int*   cursor= (int*)  alloc((size_t)NN * 4);
  int*   sums  = (int*)  alloc(512);
  u32*   xpk   = (u32*)  alloc((size_t)NN * HD * 4);     // packed split x
  u32*   h1pk  = (u32*)  alloc((size_t)NN * HD2 * 4);    // packed split h1; y aliases front half
  float* sc1   = (float*)alloc((size_t)NN * 4);
  float* sc2   = (float*)alloc((size_t)NN * 4);
  u32*   wtpk[8];
  for(int i = 0; i < 8; i++) wtpk[i] = (u32*)alloc((size_t)HD * HD * 4);
  u32*   m1tpk = (u32*)alloc((size_t)HD2 * HD * 4);
  u32*   m2tpk = (u32*)alloc((size_t)HD2 * HD2 * 4);
  float* y = (float*)h1pk;   // [NN][128] fp32; dead before h1pk is written (sequential kernels)

  const int SCAN_BLOCKS = cdiv(NN, 1024);
  auto build_csr = [&](const int* rows, const int* cols, const float* vals,
                       int* rptr, int* rcol, float* rval){
    hipLaunchKernelGGL(k_zero_int, dim3(cdiv(NN, 256)), dim3(256), 0, stream, cursor, NN);
    hipLaunchKernelGGL(k_hist,     dim3(cdiv(NE, 256)), dim3(256), 0, stream, rows, cursor);
    hipLaunchKernelGGL(k_scan1,    dim3(SCAN_BLOCKS),   dim3(256), 0, stream, cursor, rptr, sums, NN);
    hipLaunchKernelGGL(k_scan2,    dim3(1),             dim3(128), 0, stream, sums, SCAN_BLOCKS);
    hipLaunchKernelGGL(k_scan3,    dim3(SCAN_BLOCKS),   dim3(256), 0, stream, rptr, cursor, sums, NN);
    hipLaunchKernelGGL(k_scatter,  dim3(cdiv(NE, 256)), dim3(256), 0, stream, rows, cols, vals, cursor, rcol, rval);
  };

  auto splitw = [&](const float* W, u32* o, int K, int N){
    int total = K * N;
    hipLaunchKernelGGL(k_splitw, dim3(cdiv(total, 256)), dim3(256), 0, stream, W, o, K, N, total);
  };
  for(int i = 0; i < 8; i++) splitw(w[i], wtpk[i], HD, HD);
  splitw(m1, m1tpk, HD, HD2);
  splitw(m2, m2tpk, HD2, HD2);

  const int GX = cdiv(NN, 128);   // 782
  auto mlp = [&](float* score){
    hipLaunchKernelGGL((k_mfma_gemm<1>), dim3(GX, 2), dim3(256), 0, stream,
                       xpk, m1tpk, b1, (float*)nullptr, h1pk,
                       (const float*)nullptr, (float*)nullptr, NN, HD, HD2);
    hipLaunchKernelGGL((k_mfma_gemm<2>), dim3(GX, 2), dim3(256), 0, stream,
                       h1pk, m2tpk, b2, (float*)nullptr, (u32*)nullptr,
                       m3, score, NN, HD2, HD2);
  };

  auto branch = [&](const int* rptr, const int* rcol, const float* rval, float* score){
    hipLaunchKernelGGL((k_spmm<true>), dim3(cdiv(NN, 4)), dim3(256), 0, stream,
                       rptr, rcol, rval, w1, xpk);
    mlp(score);
    for(int i = 0; i < 8; i++){
      hipLaunchKernelGGL((k_mfma_gemm<0>), dim3(GX, 1), dim3(256), 0, stream,
                         xpk, wtpk[i], (const float*)nullptr, y, (u32*)nullptr,
                         (const float*)nullptr, (float*)nullptr, NN, HD, HD);
      if(i < 7)
        hipLaunchKernelGGL((k_spmm<true>),  dim3(cdiv(NN, 4)), dim3(256), 0, stream,
                           rptr, rcol, rval, y, xpk);
      else
        hipLaunchKernelGGL((k_spmm<false>), dim3(cdiv(NN, 4)), dim3(256), 0, stream,
                           rptr, rcol, rval, y, xpk);
      mlp(score);
    }
  };

  build_csr(a1r, a1c, a1v, c1ptr, c1col, c1val);
  build_csr(a2r, a2c, a2v, c2ptr, c2col, c2val);
  hipLaunchKernelGGL(k_zero_f2, dim3(cdiv(NN, 256)), dim3(256), 0, stream, sc1, sc2, NN);
  branch(c1ptr, c1col, c1val, sc1);
  branch(c2ptr, c2col, c2val, sc2);
  hipLaunchKernelGGL(k_final, dim3(cdiv(NN, 256)), dim3(256), 0, stream, sc1, sc2, b3, out);
}

// Round 6
// 4847.329 us; speedup vs baseline: 1.2269x; 1.0027x over previous
//
#include <hip/hip_runtime.h>
#include <hip/hip_fp16.h>

#define NN 100000
#define NE 1600000
#define HD 128
#define HD2 256

typedef unsigned int u32;
typedef unsigned short u16;
typedef _Float16 half8 __attribute__((ext_vector_type(8)));
typedef float floatx4 __attribute__((ext_vector_type(4)));

static inline int cdiv(int a, int b){ return (a + b - 1) / b; }

// ---- split-fp16 packing: x ~= h + l * 2^-12, l pre-scaled by 4096 ----
__device__ __forceinline__ u32 split_pack(float v){
  __half h;
  if(fabsf(v) < 6.103515625e-05f) h = __ushort_as_half((u16)0);
  else h = __float2half_rn(v);
  float hf = __half2float(h);
  __half l = __float2half_rn((v - hf) * 4096.0f);
  return (u32)__half_as_ushort(h) | ((u32)__half_as_ushort(l) << 16);
}

// ---------------- utility kernels ----------------
__global__ void k_zero_int(int* __restrict__ p, int n){
  int i = blockIdx.x * 256 + threadIdx.x;
  if(i < n) p[i] = 0;
}

__global__ void k_zero_f(float* __restrict__ p, int n){
  int i = blockIdx.x * 256 + threadIdx.x;
  if(i < n) p[i] = 0.f;
}

// ---------------- batched CSR build (blockIdx.y = adjacency index) ----------------
__global__ void k_hist2(const int* __restrict__ r0, const int* __restrict__ r1,
                        int* __restrict__ cnt){
  int e = blockIdx.x * 256 + threadIdx.x;
  if(e < NE){
    const int* rows = blockIdx.y ? r1 : r0;
    atomicAdd(&cnt[blockIdx.y * NN + rows[e]], 1);
  }
}

__global__ void k_scan1b(const int* __restrict__ cnt, int* __restrict__ p0,
                         int* __restrict__ p1, int* __restrict__ sums, int n){
  __shared__ int sh[256];
  int z = blockIdx.y;
  const int* c = cnt + z * n;
  int* part = z ? p1 : p0;
  int* sm = sums + z * 128;
  int tid = threadIdx.x;
  int base = blockIdx.x * 1024 + tid * 4;
  int v0 = (base + 0 < n) ? c[base + 0] : 0;
  int v1 = (base + 1 < n) ? c[base + 1] : 0;
  int v2 = (base + 2 < n) ? c[base + 2] : 0;
  int v3 = (base + 3 < n) ? c[base + 3] : 0;
  int s = v0 + v1 + v2 + v3;
  sh[tid] = s;
  __syncthreads();
  for(int d = 1; d < 256; d <<= 1){
    int t = (tid >= d) ? sh[tid - d] : 0;
    __syncthreads();
    sh[tid] += t;
    __syncthreads();
  }
  int excl = sh[tid] - s;
  if(tid == 255) sm[blockIdx.x] = sh[255];
  if(base + 0 < n) part[base + 0] = excl;
  if(base + 1 < n) part[base + 1] = excl + v0;
  if(base + 2 < n) part[base + 2] = excl + v0 + v1;
  if(base + 3 < n) part[base + 3] = excl + v0 + v1 + v2;
}

__global__ void k_scan2b(int* __restrict__ sums, int nb){
  __shared__ int sh[128];
  int* s = sums + blockIdx.x * 128;
  int tid = threadIdx.x;
  int v = (tid < nb) ? s[tid] : 0;
  sh[tid] = v;
  __syncthreads();
  for(int d = 1; d < 128; d <<= 1){
    int t = (tid >= d) ? sh[tid - d] : 0;
    __syncthreads();
    sh[tid] += t;
    __syncthreads();
  }
  if(tid < nb) s[tid] = sh[tid] - v;
}

__global__ void k_scan3b(int* __restrict__ r0, int* __restrict__ r1,
                         int* __restrict__ cursor, const int* __restrict__ sums, int n){
  int z = blockIdx.y;
  int* rowptr = z ? r1 : r0;
  int* cur = cursor + z * n;
  int off = sums[z * 128 + blockIdx.x];
  int tid = threadIdx.x;
  int base = blockIdx.x * 1024 + tid * 4;
  #pragma unroll
  for(int j = 0; j < 4; j++){
    int idx = base + j;
    if(idx < n){ int r = rowptr[idx] + off; rowptr[idx] = r; cur[idx] = r; }
  }
  if(blockIdx.x == 0 && tid == 0) rowptr[n] = NE;
}

__global__ void k_scatter2(const int* __restrict__ r0, const int* __restrict__ c0,
                           const float* __restrict__ v0,
                           const int* __restrict__ r1, const int* __restrict__ c1,
                           const float* __restrict__ v1,
                           int* __restrict__ cursor,
                           int* __restrict__ oc0, float* __restrict__ ov0,
                           int* __restrict__ oc1, float* __restrict__ ov1){
  int e = blockIdx.x * 256 + threadIdx.x;
  if(e < NE){
    int z = blockIdx.y;
    const int* rows = z ? r1 : r0;
    const int* cols = z ? c1 : c0;
    const float* vals = z ? v1 : v0;
    int* cur = cursor + z * NN;
    int* ocol = z ? oc1 : oc0;
    float* oval = z ? ov1 : ov0;
    int r = rows[e];
    int pp = atomicAdd(&cur[r], 1);
    ocol[pp] = cols[e];
    oval[pp] = vals[e];
  }
}

// weight pre-split: W is [K][N] row-major fp32; out is packed [N][K] (transposed)
__global__ void k_splitw(const float* __restrict__ W, u32* __restrict__ out,
                         int K, int N, int total){
  int idx = blockIdx.x * 256 + threadIdx.x;
  if(idx < total){
    int n = idx / K, k = idx - n * K;
    out[idx] = split_pack(W[(size_t)k * N + n]);
  }
}

// ---------------- SpMM: one wave per node; relu (+ optional l2norm); packed-split output ----
// blockIdx.z selects branch (CSR set + X source); output row = z*NN + node.
template<bool NORM>
__global__ void k_spmm(const int* __restrict__ rp0, const int* __restrict__ col0,
                       const float* __restrict__ val0,
                       const int* __restrict__ rp1, const int* __restrict__ col1,
                       const float* __restrict__ val1,
                       const float* __restrict__ X0, const float* __restrict__ X1,
                       u32* __restrict__ outpk){
  int z = blockIdx.z;
  const int* rowptr = z ? rp1 : rp0;
  const int* col    = z ? col1 : col0;
  const float* val  = z ? val1 : val0;
  const float* X    = z ? X1 : X0;
  int node = (blockIdx.x << 2) + (threadIdx.x >> 6);
  int lane = threadIdx.x & 63;
  if(node >= NN) return;
  int s = rowptr[node], e = rowptr[node + 1];
  float ax = 0.f, ay = 0.f, bx = 0.f, by = 0.f;
  float cx = 0.f, cy = 0.f, dx = 0.f, dy = 0.f;
  int i = s;
  for(; i + 15 < e; i += 16){
    int c[16]; float v[16]; float2 xx[16];
    #pragma unroll
    for(int j = 0; j < 16; j++){ c[j] = col[i + j]; v[j] = val[i + j]; }
    #pragma unroll
    for(int j = 0; j < 16; j++) xx[j] = *(const float2*)(X + (size_t)c[j] * HD + lane * 2);
    #pragma unroll
    for(int j = 0; j < 16; j += 4){
      ax += v[j] * xx[j].x + v[j+1] * xx[j+1].x;
      ay += v[j] * xx[j].y + v[j+1] * xx[j+1].y;
      bx += v[j+2] * xx[j+2].x + v[j+3] * xx[j+3].x;
      by += v[j+2] * xx[j+2].y + v[j+3] * xx[j+3].y;
    }
  }
  for(; i + 3 < e; i += 4){
    int   e0 = col[i],   e1 = col[i + 1], e2 = col[i + 2], e3 = col[i + 3];
    float f0 = val[i],   f1 = val[i + 1], f2 = val[i + 2], f3 = val[i + 3];
    float2 x0 = *(const float2*)(X + (size_t)e0 * HD + lane * 2);
    float2 x1 = *(const float2*)(X + (size_t)e1 * HD + lane * 2);
    float2 x2 = *(const float2*)(X + (size_t)e2 * HD + lane * 2);
    float2 x3 = *(const float2*)(X + (size_t)e3 * HD + lane * 2);
    ax += f0 * x0.x + f1 * x1.x;  ay += f0 * x0.y + f1 * x1.y;
    bx += f2 * x2.x + f3 * x3.x;  by += f2 * x2.y + f3 * x3.y;
  }
  for(; i < e; i++){
    int c = col[i]; float v = val[i];
    float2 xv = *(const float2*)(X + (size_t)c * HD + lane * 2);
    ax += v * xv.x; ay += v * xv.y;
  }
  ax += bx + cx + dx;
  ay += by + cy + dy;
  ax = fmaxf(ax, 0.f);
  ay = fmaxf(ay, 0.f);
  if(NORM){
    float ss = ax * ax + ay * ay;
    #pragma unroll
    for(int o = 32; o >= 1; o >>= 1) ss += __shfl_xor(ss, o, 64);
    float scale = 1.f / fmaxf(sqrtf(ss), 1e-12f);
    ax *= scale; ay *= scale;
  }
  size_t gnode = (size_t)(z * NN + node);
  *(uint2*)(outpk + gnode * HD + lane * 2) = make_uint2(split_pack(ax), split_pack(ay));
}

// ---------------- split-fp16 MFMA GEMM (round-2-verbatim inner loop) ----------------
// A: packed [M][K]; Bt: packed [N][K] (pre-transposed).
// MODE 0: Yout[m][n] = A@B; MODE 1: Hout = pack(relu(A@B+bias));
// MODE 2: score[m] += sum_n relu(A@B+bias)[m][n]*m3[n].
template<int MODE>
__launch_bounds__(256, 2)
__global__ void k_mfma_gemm(const u32* __restrict__ Apk, const u32* __restrict__ Btpk,
                            const float* __restrict__ bias, float* __restrict__ Yout,
                            u32* __restrict__ Hout, const float* __restrict__ m3,
                            float* __restrict__ score, int M, int K, int N){
  __shared__ unsigned short As_h[128 * 40], As_l[128 * 40];
  __shared__ unsigned short Bs_h[128 * 40], Bs_l[128 * 40];
  const int tid = threadIdx.x;
  const int lane = tid & 63, wid = tid >> 6;
  const int lm = lane & 15, lg = lane >> 4;
  const int mq = (wid & 1) * 64, nq = (wid >> 1) * 64;
  const int m0 = blockIdx.x * 128, n0 = blockIdx.y * 128;

  floatx4 accA[4][4], accB[4][4];
  #pragma unroll
  for(int i = 0; i < 4; i++)
    #pragma unroll
    for(int j = 0; j < 4; j++){
      accA[i][j] = (floatx4){0.f, 0.f, 0.f, 0.f};
      accB[i][j] = (floatx4){0.f, 0.f, 0.f, 0.f};
    }

  for(int k0 = 0; k0 < K; k0 += 32){
    uint4 av[4], bv[4];
    #pragma unroll
    for(int j = 0; j < 4; j++){
      int li = tid + j * 256;
      int row = li >> 3, kc = (li & 7) * 4;
      int ar = m0 + row; if(ar >= M) ar = M - 1;
      av[j] = *(const uint4*)(Apk + (size_t)ar * K + k0 + kc);
      bv[j] = *(const uint4*)(Btpk + (size_t)(n0 + row) * K + k0 + kc);
    }
    __syncthreads();
    #pragma unroll
    for(int j = 0; j < 4; j++){
      int li = tid + j * 256;
      int row = li >> 3, kc = (li & 7) * 4;
      int base = row * 40 + kc;
      ushort4 h, l;
      h.x = (u16)(av[j].x & 0xffff); l.x = (u16)(av[j].x >> 16);
      h.y = (u16)(av[j].y & 0xffff); l.y = (u16)(av[j].y >> 16);
      h.z = (u16)(av[j].z & 0xffff); l.z = (u16)(av[j].z >> 16);
      h.w = (u16)(av[j].w & 0xffff); l.w = (u16)(av[j].w >> 16);
      *(ushort4*)&As_h[base] = h;
      *(ushort4*)&As_l[base] = l;
      h.x = (u16)(bv[j].x & 0xffff); l.x = (u16)(bv[j].x >> 16);
      h.y = (u16)(bv[j].y & 0xffff); l.y = (u16)(bv[j].y >> 16);
      h.z = (u16)(bv[j].z & 0xffff); l.z = (u16)(bv[j].z >> 16);
      h.w = (u16)(bv[j].w & 0xffff); l.w = (u16)(bv[j].w >> 16);
      *(ushort4*)&Bs_h[base] = h;
      *(ushort4*)&Bs_l[base] = l;
    }
    __syncthreads();

    half8 fa_h[4], fa_l[4], fb_h[4], fb_l[4];
    #pragma unroll
    for(int s = 0; s < 4; s++){
      int ra = (mq + s * 16 + lm) * 40 + lg * 8;
      fa_h[s] = *(const half8*)&As_h[ra];
      fa_l[s] = *(const half8*)&As_l[ra];
      int rb = (nq + s * 16 + lm) * 40 + lg * 8;
      fb_h[s] = *(const half8*)&Bs_h[rb];
      fb_l[s] = *(const half8*)&Bs_l[rb];
    }
    #pragma unroll
    for(int i = 0; i < 4; i++)
      #pragma unroll
      for(int j = 0; j < 4; j++){
        accA[i][j] = __builtin_amdgcn_mfma_f32_16x16x32_f16(fa_h[i], fb_h[j], accA[i][j], 0, 0, 0);
        accB[i][j] = __builtin_amdgcn_mfma_f32_16x16x32_f16(fa_h[i], fb_l[j], accB[i][j], 0, 0, 0);
        accB[i][j] = __builtin_amdgcn_mfma_f32_16x16x32_f16(fa_l[i], fb_h[j], accB[i][j], 0, 0, 0);
      }
  }

  const float inv4096 = 1.f / 4096.f;
  if(MODE == 0){
    #pragma unroll
    for(int i = 0; i < 4; i++)
      #pragma unroll
      for(int r = 0; r < 4; r++){
        int m = m0 + mq + i * 16 + lg * 4 + r;
        if(m < M){
          #pragma unroll
          for(int j = 0; j < 4; j++){
            int c = n0 + nq + j * 16 + lm;
            Yout[(size_t)m * N + c] = accA[i][j][r] + accB[i][j][r] * inv4096;
          }
        }
      }
  } else if(MODE == 1){
    #pragma unroll
    for(int i = 0; i < 4; i++)
      #pragma unroll
      for(int r = 0; r < 4; r++){
        int m = m0 + mq + i * 16 + lg * 4 + r;
        if(m < M){
          #pragma unroll
          for(int j = 0; j < 4; j++){
            int c = n0 + nq + j * 16 + lm;
            float v = fmaxf(accA[i][j][r] + accB[i][j][r] * inv4096 + bias[c], 0.f);
            Hout[(size_t)m * N + c] = split_pack(v);
          }
        }
      }
  } else {
    #pragma unroll
    for(int i = 0; i < 4; i++)
      #pragma unroll
      for(int r = 0; r < 4; r++){
        float s = 0.f;
        #pragma unroll
        for(int j = 0; j < 4; j++){
          int c = n0 + nq + j * 16 + lm;
          float v = fmaxf(accA[i][j][r] + accB[i][j][r] * inv4096 + bias[c], 0.f);
          s = fmaf(v, m3[c], s);
        }
        s += __shfl_xor(s, 1, 64);
        s += __shfl_xor(s, 2, 64);
        s += __shfl_xor(s, 4, 64);
        s += __shfl_xor(s, 8, 64);
        int m = m0 + mq + i * 16 + lg * 4 + r;
        if(lm == 0 && m < M) atomicAdd(&score[m], s);
      }
  }
}

__global__ void k_final(const float* __restrict__ sc, const float* __restrict__ b3,
                        float* __restrict__ out){
  int i = blockIdx.x * 256 + threadIdx.x;
  if(i < NN){
    float b = 9.f * b3[0];
    out[i] = (sc[i] + b) * (sc[NN + i] + b);
  }
}

// ---------------- launcher ----------------
extern "C" void kernel_launch(void* const* d_in, const int* in_sizes, int n_in,
                              void* d_out, int out_size, void* d_ws, size_t ws_size,
                              hipStream_t stream){
  const int*   a1r = (const int*)d_in[0];
  const int*   a1c = (const int*)d_in[1];
  const float* a1v = (const float*)d_in[2];
  const int*   a2r = (const int*)d_in[3];
  const int*   a2c = (const int*)d_in[4];
  const float* a2v = (const float*)d_in[5];
  const float* w1  = (const float*)d_in[6];
  const float* w[8];
  for(int i = 0; i < 8; i++) w[i] = (const float*)d_in[7 + i];
  const float* m1 = (const float*)d_in[15];
  const float* b1 = (const float*)d_in[16];
  const float* m2 = (const float*)d_in[17];
  const float* b2 = (const float*)d_in[18];
  const float* m3 = (const float*)d_in[19];
  const float* b3 = (const float*)d_in[20];
  float* out = (float*)d_out;

  char* base = (char*)d_ws;
  size_t off = 0;
  auto alloc = [&](size_t bytes) -> char* {
    char* r = base + off;
    off += (bytes + 255) & ~(size_t)255;
    return r;
  };
  // fixed small buffers
  int*   c1ptr = (int*)  alloc((size_t)(NN + 1) * 4);
  int*   c1col = (int*)  alloc((size_t)NE * 4);
  float* c1val = (float*)alloc((size_t)NE * 4);
  int*   c2ptr = (int*)  alloc((size_t)(NN + 1) * 4);
  int*   c2col = (int*)  alloc((size_t)NE * 4);
  float* c2val = (float*)alloc((size_t)NE * 4);
  int*   cursor= (int*)  alloc((size_t)2 * NN * 4);
  int*   sums  = (int*)  alloc(1024);
  float* sc    = (float*)alloc((size_t)2 * NN * 4);
  u32*   wtpk[8];
  for(int i = 0; i < 8; i++) wtpk[i] = (u32*)alloc((size_t)HD * HD * 4);
  u32*   m1tpk = (u32*)alloc((size_t)HD2 * HD * 4);
  u32*   m2tpk = (u32*)alloc((size_t)HD2 * HD2 * 4);

  // big state buffers: batched (2NN rows) if workspace allows, else per-branch (NN rows)
  size_t fixed = off;
  size_t need_batched = fixed + (((size_t)2*NN*HD*4 + 255) & ~(size_t)255)
                              + (((size_t)2*NN*HD2*4 + 255) & ~(size_t)255);
  bool batched = (ws_size >= need_batched);
  int MB = batched ? 2 * NN : NN;                  // GEMM M
  u32*   xpk  = (u32*)alloc((size_t)MB * HD * 4);  // packed split x
  u32*   h1pk = (u32*)alloc((size_t)MB * HD2 * 4); // packed split h1 (y aliases front)
  float* y = (float*)h1pk;                         // [MB][128] fp32, disjoint lifetime vs h1

  // ---- batched CSR build (both adjacencies in one set of launches) ----
  hipLaunchKernelGGL(k_zero_int, dim3(cdiv(2 * NN, 256)), dim3(256), 0, stream, cursor, 2 * NN);
  hipLaunchKernelGGL(k_hist2, dim3(cdiv(NE, 256), 2), dim3(256), 0, stream, a1r, a2r, cursor);
  const int SCAN_BLOCKS = cdiv(NN, 1024);
  hipLaunchKernelGGL(k_scan1b, dim3(SCAN_BLOCKS, 2), dim3(256), 0, stream, cursor, c1ptr, c2ptr, sums, NN);
  hipLaunchKernelGGL(k_scan2b, dim3(2), dim3(128), 0, stream, sums, SCAN_BLOCKS);
  hipLaunchKernelGGL(k_scan3b, dim3(SCAN_BLOCKS, 2), dim3(256), 0, stream, c1ptr, c2ptr, cursor, sums, NN);
  hipLaunchKernelGGL(k_scatter2, dim3(cdiv(NE, 256), 2), dim3(256), 0, stream,
                     a1r, a1c, a1v, a2r, a2c, a2v, cursor, c1col, c1val, c2col, c2val);

  auto splitw = [&](const float* W, u32* o, int K, int N){
    int total = K * N;
    hipLaunchKernelGGL(k_splitw, dim3(cdiv(total, 256)), dim3(256), 0, stream, W, o, K, N, total);
  };
  for(int i = 0; i < 8; i++) splitw(w[i], wtpk[i], HD, HD);
  splitw(m1, m1tpk, HD, HD2);
  splitw(m2, m2tpk, HD2, HD2);

  hipLaunchKernelGGL(k_zero_f, dim3(cdiv(2 * NN, 256)), dim3(256), 0, stream, sc, 2 * NN);

  auto mlp = [&](int M, float* score){
    int gx = cdiv(M, 128);
    hipLaunchKernelGGL((k_mfma_gemm<1>), dim3(gx, 2), dim3(256), 0, stream,
                       xpk, m1tpk, b1, (float*)nullptr, h1pk,
                       (const float*)nullptr, (float*)nullptr, M, HD, HD2);
    hipLaunchKernelGGL((k_mfma_gemm<2>), dim3(gx, 2), dim3(256), 0, stream,
                       h1pk, m2tpk, b2, (float*)nullptr, (u32*)nullptr,
                       m3, score, M, HD2, HD2);
  };

  if(batched){
    // both branches in lockstep, GEMMs at M=2NN, SpMM with grid.z=2
    hipLaunchKernelGGL((k_spmm<true>), dim3(cdiv(NN, 4), 1, 2), dim3(256), 0, stream,
                       c1ptr, c1col, c1val, c2ptr, c2col, c2val, w1, w1, xpk);
    mlp(2 * NN, sc);
    for(int i = 0; i < 8; i++){
      hipLaunchKernelGGL((k_mfma_gemm<0>), dim3(cdiv(2 * NN, 128), 1), dim3(256), 0, stream,
                         xpk, wtpk[i], (const float*)nullptr, y, (u32*)nullptr,
                         (const float*)nullptr, (float*)nullptr, 2 * NN, HD, HD);
      if(i < 7)
        hipLaunchKernelGGL((k_spmm<true>), dim3(cdiv(NN, 4), 1, 2), dim3(256), 0, stream,
                           c1ptr, c1col, c1val, c2ptr, c2col, c2val,
                           y, y + (size_t)NN * HD, xpk);
      else
        hipLaunchKernelGGL((k_spmm<false>), dim3(cdiv(NN, 4), 1, 2), dim3(256), 0, stream,
                           c1ptr, c1col, c1val, c2ptr, c2col, c2val,
                           y, y + (size_t)NN * HD, xpk);
      mlp(2 * NN, sc);
    }
  } else {
    // serial fallback: one branch at a time, buffers reused
    for(int b = 0; b < 2; b++){
      const int* rp = b ? c2ptr : c1ptr;
      const int* cc = b ? c2col : c1col;
      const float* vv = b ? c2val : c1val;
      float* score = sc + (size_t)b * NN;
      hipLaunchKernelGGL((k_spmm<true>), dim3(cdiv(NN, 4), 1, 1), dim3(256), 0, stream,
                         rp, cc, vv, rp, cc, vv, w1, w1, xpk);
      mlp(NN, score);
      for(int i = 0; i < 8; i++){
        hipLaunchKernelGGL((k_mfma_gemm<0>), dim3(cdiv(NN, 128), 1), dim3(256), 0, stream,
                           xpk, wtpk[i], (const float*)nullptr, y, (u32*)nullptr,
                           (const float*)nullptr, (float*)nullptr, NN, HD, HD);
        if(i < 7)
          hipLaunchKernelGGL((k_spmm<true>), dim3(cdiv(NN, 4), 1, 1), dim3(256), 0, stream,
                             rp, cc, vv, rp, cc, vv, y, y, xpk);
        else
          hipLaunchKernelGGL((k_spmm<false>), dim3(cdiv(NN, 4), 1, 1), dim3(256), 0, stream,
                             rp, cc, vv, rp, cc, vv, y, y, xpk);
        mlp(NN, score);
      }
    }
  }

  hipLaunchKernelGGL(k_final, dim3(cdiv(NN, 256)), dim3(256), 0, stream, sc, b3, out);
}